// Round 5
// baseline (5154.034 us; speedup 1.0000x reference)
//
#include <hip/hip_runtime.h>
#include <hip/hip_bf16.h>
#include <hip/hip_cooperative_groups.h>

namespace cg = cooperative_groups;

#define NN 50000
#define EE 800000
#define GG 64
#define LL 3
#define CC 4
#define HH 64
#define BN_EPS 1e-5f
#define NSHADOW 16
#define SBLK 196          // ceil(NN/256) blocks for node-parallel setup
#define MEGA_BLOCKS 1024  // desired cooperative grid (clamped by occupancy query)

// NOTE: harness passes ALL integer inputs as int32 (edge_index/batch included).

// ---------------- setup kernels ----------------

__global__ void k_deg(const int* __restrict__ dst, int* __restrict__ deg) {
    int e = blockIdx.x * blockDim.x + threadIdx.x;
    if (e < EE) atomicAdd(&deg[dst[e]], 1);
}

__global__ void k_hist(const int* __restrict__ labels, int* __restrict__ blockcnt) {
    __shared__ int cnt[CC];
    int tid = threadIdx.x;
    if (tid < CC) cnt[tid] = 0;
    __syncthreads();
    int i = blockIdx.x * 256 + tid;
    if (i < NN) atomicAdd(&cnt[labels[i]], 1);
    __syncthreads();
    if (tid < CC) blockcnt[tid * SBLK + blockIdx.x] = cnt[tid];
}

__global__ __launch_bounds__(256) void k_cscan(const int* __restrict__ blockcnt,
                                               int* __restrict__ coffs,
                                               int* __restrict__ ccount) {
    __shared__ int s[CC][256];
    int t = threadIdx.x;
    int own[CC];
    for (int c = 0; c < CC; c++) {
        own[c] = (t < SBLK) ? blockcnt[c * SBLK + t] : 0;
        s[c][t] = own[c];
    }
    __syncthreads();
    for (int off = 1; off < 256; off <<= 1) {
        int v[CC];
        for (int c = 0; c < CC; c++) v[c] = (t >= off) ? s[c][t - off] : 0;
        __syncthreads();
        for (int c = 0; c < CC; c++) s[c][t] += v[c];
        __syncthreads();
    }
    if (t < SBLK)
        for (int c = 0; c < CC; c++) coffs[c * SBLK + t] = s[c][t] - own[c];
    if (t == 0)
        for (int c = 0; c < CC; c++) ccount[c] = s[c][255];
}

__global__ void k_cfill(const int* __restrict__ labels, const int* __restrict__ coffs,
                        int* __restrict__ clist) {
    __shared__ int pos[CC];
    int tid = threadIdx.x;
    if (tid < CC) pos[tid] = coffs[tid * SBLK + blockIdx.x];
    __syncthreads();
    int i = blockIdx.x * 256 + tid;
    if (i < NN) {
        int c = labels[i];
        int p = atomicAdd(&pos[c], 1);
        clist[c * NN + p] = i;
    }
}

__global__ __launch_bounds__(256) void k_dscan1(const int* __restrict__ deg,
                                                int* __restrict__ rowptr,
                                                int* __restrict__ dpart) {
    __shared__ int s[256];
    int tid = threadIdx.x;
    int i = blockIdx.x * 256 + tid;
    int v = (i < NN) ? deg[i] : 0;
    s[tid] = v;
    __syncthreads();
    for (int off = 1; off < 256; off <<= 1) {
        int u = (tid >= off) ? s[tid - off] : 0;
        __syncthreads();
        s[tid] += u;
        __syncthreads();
    }
    if (i < NN) rowptr[i] = s[tid] - v;  // local exclusive
    if (tid == 255) dpart[blockIdx.x] = s[255];
}

__global__ __launch_bounds__(256) void k_dscan2(int* __restrict__ dpart,
                                                int* __restrict__ dbase,
                                                int* __restrict__ rowptr) {
    __shared__ int s[256];
    int tid = threadIdx.x;
    int v = (tid < SBLK) ? dpart[tid] : 0;
    s[tid] = v;
    __syncthreads();
    for (int off = 1; off < 256; off <<= 1) {
        int u = (tid >= off) ? s[tid - off] : 0;
        __syncthreads();
        s[tid] += u;
        __syncthreads();
    }
    if (tid < SBLK) dbase[tid] = s[tid] - v;
    if (tid == 0) rowptr[NN] = EE;
}

__global__ __launch_bounds__(256) void k_dscan3(int* __restrict__ rowptr,
                                                const int* __restrict__ dbase,
                                                int* __restrict__ cursor) {
    int i = blockIdx.x * 256 + threadIdx.x;
    if (i < NN) {
        int r = rowptr[i] + dbase[blockIdx.x];
        rowptr[i] = r;
        cursor[i] = r;
    }
}

__global__ void k_fill(const int* __restrict__ src, const int* __restrict__ dst,
                       int* __restrict__ cursor, int* __restrict__ adj) {
    int e = blockIdx.x * blockDim.x + threadIdx.x;
    if (e < EE) {
        int d = dst[e];
        int pos = atomicAdd(&cursor[d], 1);
        adj[pos] = src[e];
    }
}

// ---------------- cooperative mega kernel ----------------
struct MegaP {
    float* xw;
    const int* adj;
    const int* rowptr;
    const int* clist;
    const int* ccount;
    const float* W1; const float* b1; const float* g1; const float* be1;
    const float* W2; const float* b2;
    const int* batch;
    float* z;
    float* bnacc;
    float* h1buf;
    const float* Wp1; const float* bp1; const float* gp; const float* bep;
    const float* Wp2; const float* bp2;
    float* out;
};

__global__ __launch_bounds__(256, 4) void k_mega(MegaP P) {
    cg::grid_group grid = cg::this_grid();
    const int tid = threadIdx.x;
    const int lane = tid & 63;
    const int wave = tid >> 6;
    const int li = lane & 15;
    const int sub = lane >> 4;
    const int wid = blockIdx.x * 4 + wave;
    const int nwaves = gridDim.x * 4;
    const float4* __restrict__ xw4 = (const float4*)P.xw;

    __shared__ float lds_red[4][128];
    __shared__ float lds_sc[64];
    __shared__ float lds_sh[64];
    __shared__ float lds_big[64 * 64];  // final MLP staging (block 0 only)

    for (int t = 0; t < LL; t++) {
        for (int c = 0; c < CC; c++) {
            const int tc = t * CC + c;
            const float* W1c = P.W1 + (size_t)tc * 4096;
            const float* b1c = P.b1 + (size_t)tc * 64;
            const float* W2c = P.W2 + (size_t)tc * 4096;
            const float* b2c = P.b2 + (size_t)tc * 64;
            const int* cl = P.clist + c * NN;
            const int cnt = P.ccount[c];
            float* bna = P.bnacc + (size_t)tc * NSHADOW * 128;

            // -------- phase A: gather + Lin1, BN partials --------
            float sS = 0.f, sQ = 0.f;
            for (int idx = wid; idx < cnt; idx += nwaves) {
                int node = cl[idx];
                int rb = P.rowptr[node], re = P.rowptr[node + 1];
                float4 a4 = make_float4(0.f, 0.f, 0.f, 0.f);
                if (sub == 0) a4 = xw4[node * 16 + li];  // self row (h = agg + x)
                int base = rb, rem = re - rb;
                while (rem > 0) {
                    int take = min(rem, 64);
                    int nb = P.adj[base + min(lane, take - 1)];
                    for (int j = 0; j < take; j += 16) {
                        #pragma unroll
                        for (int u = 0; u < 4; u++) {
                            int jj = j + 4 * u + sub;
                            int n = __shfl(nb, jj < take ? jj : 0);
                            if (jj < take) {
                                float4 v = xw4[n * 16 + li];
                                a4.x += v.x; a4.y += v.y; a4.z += v.z; a4.w += v.w;
                            }
                        }
                    }
                    base += take; rem -= take;
                }
                a4.x += __shfl_xor(a4.x, 16); a4.x += __shfl_xor(a4.x, 32);
                a4.y += __shfl_xor(a4.y, 16); a4.y += __shfl_xor(a4.y, 32);
                a4.z += __shfl_xor(a4.z, 16); a4.z += __shfl_xor(a4.z, 32);
                a4.w += __shfl_xor(a4.w, 16); a4.w += __shfl_xor(a4.w, 32);
                // Lin1: h[4k+m] lives in lane k, component m
                float s = b1c[lane];
                #pragma unroll
                for (int k = 0; k < 16; k++) {
                    float h0 = __shfl(a4.x, k);
                    float h1v = __shfl(a4.y, k);
                    float h2 = __shfl(a4.z, k);
                    float h3 = __shfl(a4.w, k);
                    s += h0 * W1c[(4 * k + 0) * 64 + lane];
                    s += h1v * W1c[(4 * k + 1) * 64 + lane];
                    s += h2 * W1c[(4 * k + 2) * 64 + lane];
                    s += h3 * W1c[(4 * k + 3) * 64 + lane];
                }
                P.h1buf[(size_t)idx * 64 + lane] = s;
                sS += s; sQ += s * s;
            }
            lds_red[wave][lane] = sS;
            lds_red[wave][64 + lane] = sQ;
            __syncthreads();
            if (tid < 128) {
                float v = lds_red[0][tid] + lds_red[1][tid] + lds_red[2][tid] + lds_red[3][tid];
                atomicAdd(&bna[(blockIdx.x & (NSHADOW - 1)) * 128 + tid], v);
            }
            __threadfence();
            grid.sync();
            __threadfence();

            // -------- phase C: BN + ReLU + Lin2, write xw --------
            if (tid < 64) {
                float s = 0.f, q = 0.f;
                #pragma unroll
                for (int sh = 0; sh < NSHADOW; sh++) {
                    s += bna[sh * 128 + tid];
                    q += bna[sh * 128 + 64 + tid];
                }
                float fc = fmaxf((float)cnt, 1.f);
                float mean = s / fc;
                float var = q / fc - mean * mean;
                float sc = P.g1[tc * 64 + tid] * rsqrtf(var + BN_EPS);
                lds_sc[tid] = sc;
                lds_sh[tid] = P.be1[tc * 64 + tid] - mean * sc;
            }
            __syncthreads();
            for (int idx = wid; idx < cnt; idx += nwaves) {
                float h = P.h1buf[(size_t)idx * 64 + lane];
                int node = cl[idx];
                float a = fmaxf(h * lds_sc[lane] + lds_sh[lane], 0.f);
                float s = b2c[lane];
                #pragma unroll
                for (int j = 0; j < 64; j++) {
                    s += __shfl(a, j) * W2c[j * 64 + lane];
                }
                P.xw[(size_t)node * 64 + lane] = s;
            }
            __threadfence();
            grid.sync();
            __threadfence();
        }
        // -------- pool layer t (reads xw only; overlaps with next A) --------
        {
            const int pch = (NN + nwaves - 1) / nwaves;
            int lo = wid * pch;
            if (lo < NN) {
                int hi = min(lo + pch, NN);
                float acc = 0.f;
                int curg = P.batch[lo];
                for (int n = lo; n < hi; n++) {
                    int g = P.batch[n];
                    if (g != curg) {
                        atomicAdd(&P.z[curg * (HH * LL) + t * HH + lane], acc);
                        acc = 0.f;
                        curg = g;
                    }
                    acc += P.xw[(size_t)n * 64 + lane];
                }
                atomicAdd(&P.z[curg * (HH * LL) + t * HH + lane], acc);
            }
        }
    }
    __threadfence();
    grid.sync();
    __threadfence();

    // -------- final MLP: block 0 only --------
    if (blockIdx.x == 0) {
        for (int i = tid; i < 64 * 64; i += 256) {
            int g = i >> 6, k = i & 63;
            float s = P.bp1[k];
            #pragma unroll 8
            for (int j = 0; j < HH * LL; j++) s += P.z[g * (HH * LL) + j] * P.Wp1[j * 64 + k];
            lds_big[i] = s;
        }
        __syncthreads();
        if (tid < 64) {
            float s = 0.f, q = 0.f;
            for (int g = 0; g < 64; g++) { float v = lds_big[g * 64 + tid]; s += v; q += v * v; }
            float mean = s / 64.f;
            float var = q / 64.f - mean * mean;
            float sc = P.gp[tid] * rsqrtf(var + BN_EPS);
            lds_sc[tid] = sc;
            lds_sh[tid] = P.bep[tid] - mean * sc;
        }
        __syncthreads();
        for (int i = tid; i < 64 * 64; i += 256) {
            int k = i & 63;
            lds_big[i] = fmaxf(lds_big[i] * lds_sc[k] + lds_sh[k], 0.f);
        }
        __syncthreads();
        for (int i = tid; i < 64 * 64; i += 256) {
            int g = i >> 6, o = i & 63;
            float s = P.bp2[o];
            #pragma unroll 8
            for (int k = 0; k < 64; k++) s += lds_big[g * 64 + k] * P.Wp2[k * 64 + o];
            P.out[g * 64 + o] = s;
        }
    }
}

// ---------------- fallback (non-cooperative) GIN kernels — round-3 proven ----------------
__global__ __launch_bounds__(256) void k_gin_a(
    const float* __restrict__ xw, const int* __restrict__ adj,
    const int* __restrict__ rowptr, const int* __restrict__ clist_c,
    const int* __restrict__ ccount_c, const float* __restrict__ W1,
    const float* __restrict__ b1, float* __restrict__ h1buf,
    float* __restrict__ bnacc) {
    __shared__ float lds_bn[128];
    int cnt = *ccount_c;
    int lane = threadIdx.x & 63;
    int wave = threadIdx.x >> 6;
    if (threadIdx.x < 128) lds_bn[threadIdx.x] = 0.f;
    __syncthreads();
    int nwaves = gridDim.x * 4;
    for (int idx = blockIdx.x * 4 + wave; idx < cnt; idx += nwaves) {
        int node = clist_c[idx];
        int rb = rowptr[node], re = rowptr[node + 1];
        float a0 = xw[node * 64 + lane], a1 = 0.f, a2 = 0.f, a3 = 0.f;
        int base = rb, remaining = re - rb;
        while (remaining > 0) {
            int take = min(remaining, 64);
            int nb = adj[base + min(lane, take - 1)];
            int j = 0;
            for (; j + 4 <= take; j += 4) {
                int n0 = __shfl(nb, j + 0);
                int n1 = __shfl(nb, j + 1);
                int n2 = __shfl(nb, j + 2);
                int n3 = __shfl(nb, j + 3);
                a0 += xw[n0 * 64 + lane];
                a1 += xw[n1 * 64 + lane];
                a2 += xw[n2 * 64 + lane];
                a3 += xw[n3 * 64 + lane];
            }
            for (; j < take; j++) a0 += xw[__shfl(nb, j) * 64 + lane];
            base += take; remaining -= take;
        }
        float acc = (a0 + a1) + (a2 + a3);
        float s = b1[lane];
        #pragma unroll
        for (int j = 0; j < 64; j++) s += __shfl(acc, j) * W1[j * 64 + lane];
        h1buf[(size_t)idx * 64 + lane] = s;
        atomicAdd(&lds_bn[lane], s);
        atomicAdd(&lds_bn[64 + lane], s * s);
    }
    __syncthreads();
    if (threadIdx.x < 128)
        atomicAdd(&bnacc[(blockIdx.x & (NSHADOW - 1)) * 128 + threadIdx.x], lds_bn[threadIdx.x]);
}

__global__ __launch_bounds__(256) void k_gin_c(
    float* __restrict__ xw, const int* __restrict__ clist_c,
    const int* __restrict__ ccount_c, const float* __restrict__ g1,
    const float* __restrict__ be1, const float* __restrict__ W2,
    const float* __restrict__ b2, const float* __restrict__ h1buf,
    const float* __restrict__ bnacc) {
    __shared__ float lds_scale[64];
    __shared__ float lds_shift[64];
    int cnt = *ccount_c;
    int lane = threadIdx.x & 63;
    int wave = threadIdx.x >> 6;
    if (threadIdx.x < 64) {
        float s = 0.f, q = 0.f;
        #pragma unroll
        for (int sh = 0; sh < NSHADOW; sh++) {
            s += bnacc[sh * 128 + threadIdx.x];
            q += bnacc[sh * 128 + 64 + threadIdx.x];
        }
        float fc = fmaxf((float)cnt, 1.f);
        float mean = s / fc;
        float var = q / fc - mean * mean;
        float sc = g1[threadIdx.x] * rsqrtf(var + BN_EPS);
        lds_scale[threadIdx.x] = sc;
        lds_shift[threadIdx.x] = be1[threadIdx.x] - mean * sc;
    }
    __syncthreads();
    int nwaves = gridDim.x * 4;
    for (int idx = blockIdx.x * 4 + wave; idx < cnt; idx += nwaves) {
        float h = h1buf[(size_t)idx * 64 + lane];
        float a = fmaxf(h * lds_scale[lane] + lds_shift[lane], 0.f);
        float s = b2[lane];
        #pragma unroll
        for (int j = 0; j < 64; j++) s += __shfl(a, j) * W2[j * 64 + lane];
        xw[(size_t)clist_c[idx] * 64 + lane] = s;
    }
}

__global__ void k_pool(const float* __restrict__ xw, const int* __restrict__ batch,
                       float* __restrict__ z, int t) {
    const int CHUNK = 256;
    int lane = threadIdx.x & 63;
    int wg = (blockIdx.x * blockDim.x + threadIdx.x) >> 6;
    int lo = wg * CHUNK;
    if (lo >= NN) return;
    int hi = min(lo + CHUNK, NN);
    float acc = 0.f;
    int curg = batch[lo];
    for (int n = lo; n < hi; n++) {
        int g = batch[n];
        if (g != curg) {
            atomicAdd(&z[curg * (HH * LL) + t * HH + lane], acc);
            acc = 0.f;
            curg = g;
        }
        acc += xw[(size_t)n * 64 + lane];
    }
    atomicAdd(&z[curg * (HH * LL) + t * HH + lane], acc);
}

__global__ __launch_bounds__(256) void k_final(
    const float* __restrict__ z, const float* __restrict__ Wp1,
    const float* __restrict__ bp1, const float* __restrict__ gp,
    const float* __restrict__ bep, const float* __restrict__ Wp2,
    const float* __restrict__ bp2, float* __restrict__ out) {
    __shared__ float lds[64 * 64];
    __shared__ float sscale[64];
    __shared__ float sshift[64];
    int tid = threadIdx.x;
    for (int i = tid; i < 64 * 64; i += 256) {
        int g = i >> 6, k = i & 63;
        float s = bp1[k];
        #pragma unroll 8
        for (int j = 0; j < HH * LL; j++) s += z[g * (HH * LL) + j] * Wp1[j * 64 + k];
        lds[i] = s;
    }
    __syncthreads();
    if (tid < 64) {
        float s = 0.f, q = 0.f;
        for (int g = 0; g < 64; g++) { float v = lds[g * 64 + tid]; s += v; q += v * v; }
        float mean = s / 64.f;
        float var = q / 64.f - mean * mean;
        float sc = gp[tid] * rsqrtf(var + BN_EPS);
        sscale[tid] = sc;
        sshift[tid] = bep[tid] - mean * sc;
    }
    __syncthreads();
    for (int i = tid; i < 64 * 64; i += 256) {
        int k = i & 63;
        lds[i] = fmaxf(lds[i] * sscale[k] + sshift[k], 0.f);
    }
    __syncthreads();
    for (int i = tid; i < 64 * 64; i += 256) {
        int g = i >> 6, o = i & 63;
        float s = bp2[o];
        #pragma unroll 8
        for (int k = 0; k < 64; k++) s += lds[g * 64 + k] * Wp2[k * 64 + o];
        out[g * 64 + o] = s;
    }
}

// ---------------- launch ----------------
extern "C" void kernel_launch(void* const* d_in, const int* in_sizes, int n_in,
                              void* d_out, int out_size, void* d_ws, size_t ws_size,
                              hipStream_t stream) {
    const float* x_in = (const float*)d_in[0];
    const int* labels = (const int*)d_in[1];
    const int* esrc = (const int*)d_in[2];
    const int* edst = esrc + EE;
    const int* batch = (const int*)d_in[3];
    const float* W1 = (const float*)d_in[4];
    const float* b1 = (const float*)d_in[5];
    const float* g1 = (const float*)d_in[6];
    const float* be1 = (const float*)d_in[7];
    const float* W2 = (const float*)d_in[8];
    const float* b2 = (const float*)d_in[9];
    const float* Wp1 = (const float*)d_in[10];
    const float* bp1 = (const float*)d_in[11];
    const float* gp = (const float*)d_in[12];
    const float* bep = (const float*)d_in[13];
    const float* Wp2 = (const float*)d_in[14];
    const float* bp2 = (const float*)d_in[15];
    float* out = (float*)d_out;

    char* p = (char*)d_ws;
    auto carve = [&](size_t bytes) -> void* {
        void* r = (void*)p;
        p += (bytes + 255) & ~(size_t)255;
        return r;
    };
    float* bnacc = (float*)carve((size_t)LL * CC * NSHADOW * 128 * 4);
    float* z     = (float*)carve((size_t)GG * HH * LL * 4);
    int*   deg   = (int*)carve((size_t)NN * 4);
    size_t zero_bytes = (size_t)(p - (char*)d_ws);
    int*   ccount  = (int*)carve(CC * 4);
    int*   blockcnt= (int*)carve((size_t)CC * SBLK * 4);
    int*   coffs   = (int*)carve((size_t)CC * SBLK * 4);
    int*   dpart   = (int*)carve((size_t)SBLK * 4);
    int*   dbase   = (int*)carve((size_t)SBLK * 4);
    float* xw      = (float*)carve((size_t)NN * 64 * 4);
    float* h1buf   = (float*)carve((size_t)NN * 64 * 4);
    int*   rowptr  = (int*)carve((size_t)(NN + 1) * 4);
    int*   cursor  = (int*)carve((size_t)NN * 4);
    int*   adj     = (int*)carve((size_t)EE * 4);
    int*   clist   = (int*)carve((size_t)CC * NN * 4);

    hipMemsetAsync(d_ws, 0, zero_bytes, stream);
    hipMemcpyAsync(xw, x_in, (size_t)NN * 64 * 4, hipMemcpyDeviceToDevice, stream);

    k_deg<<<(EE + 255) / 256, 256, 0, stream>>>(edst, deg);
    k_hist<<<SBLK, 256, 0, stream>>>(labels, blockcnt);
    k_cscan<<<1, 256, 0, stream>>>(blockcnt, coffs, ccount);
    k_cfill<<<SBLK, 256, 0, stream>>>(labels, coffs, clist);
    k_dscan1<<<SBLK, 256, 0, stream>>>(deg, rowptr, dpart);
    k_dscan2<<<1, 256, 0, stream>>>(dpart, dbase, rowptr);
    k_dscan3<<<SBLK, 256, 0, stream>>>(rowptr, dbase, cursor);
    k_fill<<<(EE + 255) / 256, 256, 0, stream>>>(esrc, edst, cursor, adj);

    MegaP kp;
    kp.xw = xw; kp.adj = adj; kp.rowptr = rowptr; kp.clist = clist; kp.ccount = ccount;
    kp.W1 = W1; kp.b1 = b1; kp.g1 = g1; kp.be1 = be1; kp.W2 = W2; kp.b2 = b2;
    kp.batch = batch; kp.z = z; kp.bnacc = bnacc; kp.h1buf = h1buf;
    kp.Wp1 = Wp1; kp.bp1 = bp1; kp.gp = gp; kp.bep = bep; kp.Wp2 = Wp2; kp.bp2 = bp2;
    kp.out = out;

    bool coop_done = false;
    int maxb = 0;
    hipError_t oerr = hipOccupancyMaxActiveBlocksPerMultiprocessor(&maxb, k_mega, 256, 0);
    if (oerr == hipSuccess && maxb > 0) {
        int grid = maxb * 256;  // 256 CUs on MI355X
        if (grid > MEGA_BLOCKS) grid = MEGA_BLOCKS;
        void* kargs[] = { (void*)&kp };
        hipError_t lerr = hipLaunchCooperativeKernel((void*)k_mega, dim3(grid), dim3(256),
                                                     kargs, 0, stream);
        if (lerr == hipSuccess) coop_done = true;
    }

    if (!coop_done) {
        // fallback: proven multi-kernel path
        for (int t = 0; t < LL; t++) {
            for (int c = 0; c < CC; c++) {
                int tc = t * CC + c;
                k_gin_a<<<1024, 256, 0, stream>>>(
                    xw, adj, rowptr, clist + c * NN, ccount + c,
                    W1 + (size_t)tc * 4096, b1 + (size_t)tc * 64, h1buf,
                    bnacc + (size_t)tc * NSHADOW * 128);
                k_gin_c<<<1024, 256, 0, stream>>>(
                    xw, clist + c * NN, ccount + c,
                    g1 + (size_t)tc * 64, be1 + (size_t)tc * 64,
                    W2 + (size_t)tc * 4096, b2 + (size_t)tc * 64, h1buf,
                    bnacc + (size_t)tc * NSHADOW * 128);
            }
            int pool_waves = (NN + 255) / 256;
            int pool_blocks = (pool_waves * 64 + 255) / 256;
            k_pool<<<pool_blocks, 256, 0, stream>>>(xw, batch, z, t);
        }
        k_final<<<1, 256, 0, stream>>>(z, Wp1, bp1, gp, bep, Wp2, bp2, out);
    }
}

// Round 6
// 893.676 us; speedup vs baseline: 5.7672x; 5.7672x over previous
//
#include <hip/hip_runtime.h>
#include <hip/hip_bf16.h>

#define NN 50000
#define EE 800000
#define GG 64
#define LL 3
#define CC 4
#define HH 64
#define BN_EPS 1e-5f
#define NSHADOW 16
#define SBLK 196          // ceil(NN/256) node-parallel blocks
#define GIN_BLOCKS 2048   // grid-stride GIN kernels (8192 waves)

// NOTE: harness passes ALL integer inputs as int32 (edge_index/batch included).
// NOTE: cooperative launch + grid.sync measured 4x SLOWER than kernel-boundary
//       barriers on this problem (R5: 5154us vs 1230us) — do not reintroduce.

// ---------------- setup kernels ----------------

// fused: degree count (edge-parallel) + cluster histogram (node-parallel, first SBLK blocks)
__global__ void k_deghist(const int* __restrict__ dst, int* __restrict__ deg,
                          const int* __restrict__ labels, int* __restrict__ blockcnt) {
    __shared__ int cnt[CC];
    int tid = threadIdx.x;
    bool hist = (blockIdx.x < SBLK);
    if (hist && tid < CC) cnt[tid] = 0;
    __syncthreads();
    int gid = blockIdx.x * 256 + tid;
    if (gid < EE) atomicAdd(&deg[dst[gid]], 1);
    if (hist && gid < NN) atomicAdd(&cnt[labels[gid]], 1);
    __syncthreads();
    if (hist && tid < CC) blockcnt[tid * SBLK + blockIdx.x] = cnt[tid];
}

// fused: blocks 0..SBLK-1 do local exclusive scan of deg; block SBLK does cluster scan
__global__ __launch_bounds__(256) void k_scancombo(
    const int* __restrict__ deg, int* __restrict__ rowptr, int* __restrict__ dpart,
    const int* __restrict__ blockcnt, int* __restrict__ coffs, int* __restrict__ ccount) {
    __shared__ int smem[CC * 256];
    int tid = threadIdx.x;
    if (blockIdx.x < SBLK) {
        int i = blockIdx.x * 256 + tid;
        int v = (i < NN) ? deg[i] : 0;
        smem[tid] = v;
        __syncthreads();
        for (int off = 1; off < 256; off <<= 1) {
            int u = (tid >= off) ? smem[tid - off] : 0;
            __syncthreads();
            smem[tid] += u;
            __syncthreads();
        }
        if (i < NN) rowptr[i] = smem[tid] - v;  // local exclusive
        if (tid == 255) dpart[blockIdx.x] = smem[255];
    } else {
        int own[CC];
        for (int c = 0; c < CC; c++) {
            own[c] = (tid < SBLK) ? blockcnt[c * SBLK + tid] : 0;
            smem[c * 256 + tid] = own[c];
        }
        __syncthreads();
        for (int off = 1; off < 256; off <<= 1) {
            int v[CC];
            for (int c = 0; c < CC; c++) v[c] = (tid >= off) ? smem[c * 256 + tid - off] : 0;
            __syncthreads();
            for (int c = 0; c < CC; c++) smem[c * 256 + tid] += v[c];
            __syncthreads();
        }
        if (tid < SBLK)
            for (int c = 0; c < CC; c++) coffs[c * SBLK + tid] = smem[c * 256 + tid] - own[c];
        if (tid == 0)
            for (int c = 0; c < CC; c++) ccount[c] = smem[c * 256 + 255];
    }
}

__global__ __launch_bounds__(256) void k_dscan2(int* __restrict__ dpart,
                                                int* __restrict__ dbase,
                                                int* __restrict__ rowptr) {
    __shared__ int s[256];
    int tid = threadIdx.x;
    int v = (tid < SBLK) ? dpart[tid] : 0;
    s[tid] = v;
    __syncthreads();
    for (int off = 1; off < 256; off <<= 1) {
        int u = (tid >= off) ? s[tid - off] : 0;
        __syncthreads();
        s[tid] += u;
        __syncthreads();
    }
    if (tid < SBLK) dbase[tid] = s[tid] - v;
    if (tid == 0) rowptr[NN] = EE;
}

// fused: rowptr globalization + cursor init + cluster-list fill
__global__ __launch_bounds__(256) void k_cfill_dscan3(
    int* __restrict__ rowptr, const int* __restrict__ dbase, int* __restrict__ cursor,
    const int* __restrict__ labels, const int* __restrict__ coffs, int* __restrict__ clist) {
    __shared__ int pos[CC];
    int tid = threadIdx.x;
    if (tid < CC) pos[tid] = coffs[tid * SBLK + blockIdx.x];
    __syncthreads();
    int i = blockIdx.x * 256 + tid;
    if (i < NN) {
        int r = rowptr[i] + dbase[blockIdx.x];
        rowptr[i] = r;
        cursor[i] = r;
        int c = labels[i];
        int p = atomicAdd(&pos[c], 1);
        clist[c * NN + p] = i;
    }
}

__global__ void k_fill(const int* __restrict__ src, const int* __restrict__ dst,
                       int* __restrict__ cursor, int* __restrict__ adj) {
    int e = blockIdx.x * blockDim.x + threadIdx.x;
    if (e < EE) {
        int d = dst[e];
        int pos = atomicAdd(&cursor[d], 1);
        adj[pos] = src[e];
    }
}

// ---------------- per-(t,c) kernels ----------------
// Kernel A: agg (CSR gather, 8 indep chains) + h1 = (agg+x)@W1 + b1; BN partials.
__global__ __launch_bounds__(256) void k_gin_a(
    const float* __restrict__ xw, const int* __restrict__ adj,
    const int* __restrict__ rowptr, const int* __restrict__ clist_c,
    const int* __restrict__ ccount_c, const float* __restrict__ W1,
    const float* __restrict__ b1, float* __restrict__ h1buf,
    float* __restrict__ bnacc) {
    __shared__ float lds_red[4][128];
    int cnt = *ccount_c;
    int lane = threadIdx.x & 63;
    int wave = threadIdx.x >> 6;
    int nwaves = gridDim.x * 4;
    float sS = 0.f, sQ = 0.f;
    int idx = blockIdx.x * 4 + wave;
    int node_next = (idx < cnt) ? clist_c[idx] : 0;
    for (; idx < cnt; idx += nwaves) {
        int node = node_next;
        int nidx = idx + nwaves;
        if (nidx < cnt) node_next = clist_c[nidx];  // prefetch next node id
        int rb = rowptr[node], re = rowptr[node + 1];
        float a0 = xw[node * 64 + lane];
        float a1 = 0.f, a2 = 0.f, a3 = 0.f, a4 = 0.f, a5 = 0.f, a6 = 0.f, a7 = 0.f;
        int base = rb, rem = re - rb;
        while (rem > 0) {
            int take = min(rem, 64);
            int nb = adj[base + min(lane, take - 1)];
            int j = 0;
            for (; j + 8 <= take; j += 8) {
                int n0 = __shfl(nb, j + 0);
                int n1 = __shfl(nb, j + 1);
                int n2 = __shfl(nb, j + 2);
                int n3 = __shfl(nb, j + 3);
                int n4 = __shfl(nb, j + 4);
                int n5 = __shfl(nb, j + 5);
                int n6 = __shfl(nb, j + 6);
                int n7 = __shfl(nb, j + 7);
                a0 += xw[n0 * 64 + lane];
                a1 += xw[n1 * 64 + lane];
                a2 += xw[n2 * 64 + lane];
                a3 += xw[n3 * 64 + lane];
                a4 += xw[n4 * 64 + lane];
                a5 += xw[n5 * 64 + lane];
                a6 += xw[n6 * 64 + lane];
                a7 += xw[n7 * 64 + lane];
            }
            for (; j < take; j++) a0 += xw[__shfl(nb, j) * 64 + lane];
            base += take; rem -= take;
        }
        float acc = ((a0 + a1) + (a2 + a3)) + ((a4 + a5) + (a6 + a7));
        float s = b1[lane];
        #pragma unroll
        for (int j = 0; j < 64; j++) s += __shfl(acc, j) * W1[j * 64 + lane];
        h1buf[(size_t)idx * 64 + lane] = s;
        sS += s; sQ += s * s;
    }
    lds_red[wave][lane] = sS;
    lds_red[wave][64 + lane] = sQ;
    __syncthreads();
    if (threadIdx.x < 128) {
        float v = lds_red[0][threadIdx.x] + lds_red[1][threadIdx.x] +
                  lds_red[2][threadIdx.x] + lds_red[3][threadIdx.x];
        atomicAdd(&bnacc[(blockIdx.x & (NSHADOW - 1)) * 128 + threadIdx.x], v);
    }
}

// Kernel C: scale/shift from BN stats; h2 = relu(bn(h1))@W2 + b2; x[node] = h2.
__global__ __launch_bounds__(256) void k_gin_c(
    float* __restrict__ xw, const int* __restrict__ clist_c,
    const int* __restrict__ ccount_c, const float* __restrict__ g1,
    const float* __restrict__ be1, const float* __restrict__ W2,
    const float* __restrict__ b2, const float* __restrict__ h1buf,
    const float* __restrict__ bnacc) {
    __shared__ float lds_scale[64];
    __shared__ float lds_shift[64];
    int cnt = *ccount_c;
    int lane = threadIdx.x & 63;
    int wave = threadIdx.x >> 6;
    if (threadIdx.x < 64) {
        float s = 0.f, q = 0.f;
        #pragma unroll
        for (int sh = 0; sh < NSHADOW; sh++) {
            s += bnacc[sh * 128 + threadIdx.x];
            q += bnacc[sh * 128 + 64 + threadIdx.x];
        }
        float fc = fmaxf((float)cnt, 1.f);
        float mean = s / fc;
        float var = q / fc - mean * mean;
        float sc = g1[threadIdx.x] * rsqrtf(var + BN_EPS);
        lds_scale[threadIdx.x] = sc;
        lds_shift[threadIdx.x] = be1[threadIdx.x] - mean * sc;
    }
    __syncthreads();
    int nwaves = gridDim.x * 4;
    for (int idx = blockIdx.x * 4 + wave; idx < cnt; idx += nwaves) {
        float h = h1buf[(size_t)idx * 64 + lane];
        float a = fmaxf(h * lds_scale[lane] + lds_shift[lane], 0.f);
        float s = b2[lane];
        #pragma unroll
        for (int j = 0; j < 64; j++) s += __shfl(a, j) * W2[j * 64 + lane];
        xw[(size_t)clist_c[idx] * 64 + lane] = s;
    }
}

// ---------------- pooling (batch is sorted) ----------------
__global__ void k_pool(const float* __restrict__ xw, const int* __restrict__ batch,
                       float* __restrict__ z, int t) {
    const int CHUNK = 64;
    int lane = threadIdx.x & 63;
    int wg = (blockIdx.x * blockDim.x + threadIdx.x) >> 6;
    int lo = wg * CHUNK;
    if (lo >= NN) return;
    int hi = min(lo + CHUNK, NN);
    float acc = 0.f;
    int curg = batch[lo];
    for (int n = lo; n < hi; n++) {
        int g = batch[n];
        if (g != curg) {
            atomicAdd(&z[curg * (HH * LL) + t * HH + lane], acc);
            acc = 0.f;
            curg = g;
        }
        acc += xw[(size_t)n * 64 + lane];
    }
    atomicAdd(&z[curg * (HH * LL) + t * HH + lane], acc);
}

// ---------------- final MLP (single block) ----------------
__global__ __launch_bounds__(256) void k_final(
    const float* __restrict__ z, const float* __restrict__ Wp1,
    const float* __restrict__ bp1, const float* __restrict__ gp,
    const float* __restrict__ bep, const float* __restrict__ Wp2,
    const float* __restrict__ bp2, float* __restrict__ out) {
    __shared__ float lds[64 * 64];
    __shared__ float sscale[64];
    __shared__ float sshift[64];
    int tid = threadIdx.x;
    for (int i = tid; i < 64 * 64; i += 256) {
        int g = i >> 6, k = i & 63;
        float s = bp1[k];
        #pragma unroll 8
        for (int j = 0; j < HH * LL; j++) s += z[g * (HH * LL) + j] * Wp1[j * 64 + k];
        lds[i] = s;
    }
    __syncthreads();
    if (tid < 64) {
        float s = 0.f, q = 0.f;
        for (int g = 0; g < 64; g++) { float v = lds[g * 64 + tid]; s += v; q += v * v; }
        float mean = s / 64.f;
        float var = q / 64.f - mean * mean;
        float sc = gp[tid] * rsqrtf(var + BN_EPS);
        sscale[tid] = sc;
        sshift[tid] = bep[tid] - mean * sc;
    }
    __syncthreads();
    for (int i = tid; i < 64 * 64; i += 256) {
        int k = i & 63;
        lds[i] = fmaxf(lds[i] * sscale[k] + sshift[k], 0.f);
    }
    __syncthreads();
    for (int i = tid; i < 64 * 64; i += 256) {
        int g = i >> 6, o = i & 63;
        float s = bp2[o];
        #pragma unroll 8
        for (int k = 0; k < 64; k++) s += lds[g * 64 + k] * Wp2[k * 64 + o];
        out[g * 64 + o] = s;
    }
}

// ---------------- launch ----------------
extern "C" void kernel_launch(void* const* d_in, const int* in_sizes, int n_in,
                              void* d_out, int out_size, void* d_ws, size_t ws_size,
                              hipStream_t stream) {
    const float* x_in = (const float*)d_in[0];
    const int* labels = (const int*)d_in[1];
    const int* esrc = (const int*)d_in[2];
    const int* edst = esrc + EE;
    const int* batch = (const int*)d_in[3];
    const float* W1 = (const float*)d_in[4];
    const float* b1 = (const float*)d_in[5];
    const float* g1 = (const float*)d_in[6];
    const float* be1 = (const float*)d_in[7];
    const float* W2 = (const float*)d_in[8];
    const float* b2 = (const float*)d_in[9];
    const float* Wp1 = (const float*)d_in[10];
    const float* bp1 = (const float*)d_in[11];
    const float* gp = (const float*)d_in[12];
    const float* bep = (const float*)d_in[13];
    const float* Wp2 = (const float*)d_in[14];
    const float* bp2 = (const float*)d_in[15];
    float* out = (float*)d_out;

    char* p = (char*)d_ws;
    auto carve = [&](size_t bytes) -> void* {
        void* r = (void*)p;
        p += (bytes + 255) & ~(size_t)255;
        return r;
    };
    // ---- zeroed region (one memset) ----
    float* bnacc = (float*)carve((size_t)LL * CC * NSHADOW * 128 * 4);
    float* z     = (float*)carve((size_t)GG * HH * LL * 4);
    int*   deg   = (int*)carve((size_t)NN * 4);
    size_t zero_bytes = (size_t)(p - (char*)d_ws);
    // ---- rest ----
    int*   ccount  = (int*)carve(CC * 4);
    int*   blockcnt= (int*)carve((size_t)CC * SBLK * 4);
    int*   coffs   = (int*)carve((size_t)CC * SBLK * 4);
    int*   dpart   = (int*)carve((size_t)SBLK * 4);
    int*   dbase   = (int*)carve((size_t)SBLK * 4);
    float* xw      = (float*)carve((size_t)NN * 64 * 4);
    float* h1buf   = (float*)carve((size_t)NN * 64 * 4);
    int*   rowptr  = (int*)carve((size_t)(NN + 1) * 4);
    int*   cursor  = (int*)carve((size_t)NN * 4);
    int*   adj     = (int*)carve((size_t)EE * 4);
    int*   clist   = (int*)carve((size_t)CC * NN * 4);

    hipMemsetAsync(d_ws, 0, zero_bytes, stream);
    hipMemcpyAsync(xw, x_in, (size_t)NN * 64 * 4, hipMemcpyDeviceToDevice, stream);

    k_deghist<<<(EE + 255) / 256, 256, 0, stream>>>(edst, deg, labels, blockcnt);
    k_scancombo<<<SBLK + 1, 256, 0, stream>>>(deg, rowptr, dpart, blockcnt, coffs, ccount);
    k_dscan2<<<1, 256, 0, stream>>>(dpart, dbase, rowptr);
    k_cfill_dscan3<<<SBLK, 256, 0, stream>>>(rowptr, dbase, cursor, labels, coffs, clist);
    k_fill<<<(EE + 255) / 256, 256, 0, stream>>>(esrc, edst, cursor, adj);

    for (int t = 0; t < LL; t++) {
        for (int c = 0; c < CC; c++) {
            int tc = t * CC + c;
            k_gin_a<<<GIN_BLOCKS, 256, 0, stream>>>(
                xw, adj, rowptr, clist + c * NN, ccount + c,
                W1 + (size_t)tc * 4096, b1 + (size_t)tc * 64, h1buf,
                bnacc + (size_t)tc * NSHADOW * 128);
            k_gin_c<<<GIN_BLOCKS, 256, 0, stream>>>(
                xw, clist + c * NN, ccount + c,
                g1 + (size_t)tc * 64, be1 + (size_t)tc * 64,
                W2 + (size_t)tc * 4096, b2 + (size_t)tc * 64, h1buf,
                bnacc + (size_t)tc * NSHADOW * 128);
        }
        int pool_waves = (NN + 63) / 64;
        int pool_blocks = (pool_waves * 64 + 255) / 256;
        k_pool<<<pool_blocks, 256, 0, stream>>>(xw, batch, z, t);
    }
    k_final<<<1, 256, 0, stream>>>(z, Wp1, bp1, gp, bep, Wp2, bp2, out);
}